// Round 9
// baseline (8246.621 us; speedup 1.0000x reference)
//
#include <hip/hip_runtime.h>
#include <hip/hip_bf16.h>
#include <stdint.h>

#define TT 64
#define BB 512
#define XX 1024
#define HH 1024
#define ZZ 256
#define AA 64

#define NBLK 256
#define NTHR 512
#define ROWS 16      // rows per group
#define RPG 8        // ranks per group == XCDs; rank = physical XCC_ID

typedef __bf16 bf16;
typedef bf16 bf16x8 __attribute__((ext_vector_type(8)));
typedef float f32x4 __attribute__((ext_vector_type(4)));
typedef unsigned int u32x4 __attribute__((ext_vector_type(4)));

// d_out layout (fp32): beliefs[T+1,B,H] | q_loc | q_scale | p_loc | p_scale | z_q
#define SZ_BEL ((long)(TT + 1) * BB * HH)
#define SZ_TBZ ((long)TT * BB * ZZ)
#define OFF_QL (SZ_BEL)
#define OFF_QS (OFF_QL + SZ_TBZ)
#define OFF_PL (OFF_QL + 2 * SZ_TBZ)
#define OFF_PS (OFF_QL + 3 * SZ_TBZ)
#define OFF_ZQ (OFF_QL + 4 * SZ_TBZ)

#define GLL16(g, l)                                                         \
  __builtin_amdgcn_global_load_lds(                                         \
      (__attribute__((address_space(1))) void*)(g),                         \
      (__attribute__((address_space(3))) void*)(l), 16, 0, 0)

#define MFMA(a, b, c) __builtin_amdgcn_mfma_f32_16x16x32_bf16(a, b, c, 0, 0, 0)

#define ALOAD_U32(p) __hip_atomic_load((const unsigned*)(p), __ATOMIC_RELAXED, __HIP_MEMORY_SCOPE_AGENT)
#define ASTORE_U16(p, v) __hip_atomic_store((unsigned short*)(p), (v), __ATOMIC_RELAXED, __HIP_MEMORY_SCOPE_AGENT)
#define ASTORE_U64(p, v) __hip_atomic_store((unsigned long long*)(p), (v), __ATOMIC_RELAXED, __HIP_MEMORY_SCOPE_AGENT)
#define ASTORE_U32(p, v) __hip_atomic_store((unsigned*)(p), (v), __ATOMIC_RELAXED, __HIP_MEMORY_SCOPE_AGENT)

__device__ __forceinline__ float eluf(float x) { return x > 0.f ? x : expf(x) - 1.f; }
__device__ __forceinline__ float splusf(float x) { return fmaxf(x, 0.f) + log1pf(expf(-fabsf(x))); }
__device__ __forceinline__ float sigf(float x) { return 1.f / (1.f + expf(-x)); }
__device__ __forceinline__ unsigned short bf2u(bf16 v) { return __builtin_bit_cast(unsigned short, v); }
__device__ __forceinline__ float u2f(unsigned short u) { return (float)__builtin_bit_cast(bf16, u); }
__device__ __forceinline__ bf16x8 ldg8(const bf16* p) { return *(const bf16x8*)p; }

// 16B device-coherent (bypass) load
__device__ __forceinline__ void cload16(u32x4& v, const void* p) {
  asm volatile("global_load_dwordx4 %0, %1, off sc0 sc1" : "=v"(v) : "v"(p));
}

// swizzled frag read from a 16-row x 64-col LDS k-tile (2KB, row stride 128B)
__device__ __forceinline__ bf16x8 ldfrag(const char* tile, int row, int w) {
  return *(const bf16x8*)(tile + row * 128 + (w ^ ((row & 7) << 4)));
}

// Bypass-stage a 16 x C bf16 row-major panel into swizzled 2KB LDS k-tiles.
// Each thread loads 64B CONTIGUOUS (4 x 16B) -> full-sector IF reads.
template <int C>  // 1024 (THR=512) or 256 (THR=128)
__device__ __forceinline__ void stage_bypass(const bf16* base, char* lds) {
  constexpr int THR = (2 * C) / 4;
  if (threadIdx.x < THR) {
    u32x4 v[4];
#pragma unroll
    for (int i = 0; i < 4; ++i)
      cload16(v[i], (const char*)base + (threadIdx.x * 4 + i) * 16);
    asm volatile("s_waitcnt vmcnt(0)" ::: "memory");
    __builtin_amdgcn_sched_barrier(0);
#pragma unroll
    for (int i = 0; i < 4; ++i) {
      int gb = (threadIdx.x * 4 + i) * 16;
      int row = (C == 1024) ? (gb >> 11) : (gb >> 9);
      int colb = gb & (2 * C - 1);
      int ktile = colb >> 7, cb = colb & 127;
      *(u32x4*)(lds + ktile * 2048 + row * 128 + (cb ^ ((row & 7) << 4))) = v[i];
    }
  }
}

// act tile (16 x 64, read-only input): normal cached 64B-chunk loads
__device__ __forceinline__ void stage_act(const bf16* base, char* lds) {
  if (threadIdx.x < 32) {
    u32x4 v[4];
#pragma unroll
    for (int i = 0; i < 4; ++i)
      v[i] = *(const u32x4*)((const char*)base + (threadIdx.x * 4 + i) * 16);
#pragma unroll
    for (int i = 0; i < 4; ++i) {
      int u = threadIdx.x * 4 + i;
      int row = u >> 3, cb = (u & 7) * 16;
      *(u32x4*)(lds + row * 128 + (cb ^ ((row & 7) << 4))) = v[i];
    }
  }
}

// Group-local (8-rank) barrier: per-rank arrival words (one line/group) + go.
__device__ __forceinline__ void gbar(unsigned* arr, unsigned* go, int rank, unsigned gen) {
  __syncthreads();
  if (rank == 0) {
    if (threadIdx.x > 0 && threadIdx.x < RPG) {
      while (ALOAD_U32(&arr[threadIdx.x]) < gen) __builtin_amdgcn_s_sleep(2);
    }
    if (threadIdx.x == 0) ASTORE_U32(go, gen);
  } else if (threadIdx.x == 0) {
    ASTORE_U32(&arr[rank], gen);
    while (ALOAD_U32(go) < gen) __builtin_amdgcn_s_sleep(2);
  }
  __syncthreads();
  asm volatile("" ::: "memory");
}

struct ScanArgs {
  const bf16 *Pq1, *Pqh, *Pag, *Pih, *Phh;  // frag-linear packed weights
  const bf16 *obs_pre, *act_bf;             // obs_pre: [g][t][col][16] bf16
  bf16 *h, *hid, *z, *a, *ghT;              // ghT: [g][3072 cols][16 rows]
  const float *b_q1, *b_ghh, *b_qm, *b_qs, *b_ag, *b_gih;
  const float* eps;
  float* dout;
  unsigned* bar;  // [0..1023] arrive, [1024..2047] go, [2048..] per-XCD tickets
};

__global__ __launch_bounds__(NTHR, 2) void scan_k(ScanArgs s) {
  // 96KB forces 1 block/CU -> exactly 32 blocks per XCD (grid = 256 = #CUs).
  __shared__ __align__(16) char smem[98304];
  char* aux = smem + 32768;  // obs (20.5KB) | eps (16KB) | ghT (15.4KB), per-phase
  const int tid = threadIdx.x;
  const int wid = tid >> 6, lane = tid & 63;
  const int lr = lane & 15, lk = lane >> 4;

  int xcd;
  asm volatile("s_getreg_b32 %0, hwreg(HW_REG_XCC_ID)" : "=s"(xcd));
  xcd &= 7;
  __shared__ int sgr;
  if (tid == 0) sgr = (int)atomicAdd(&s.bar[2048 + xcd * 64], 1u);
  __syncthreads();
  const int rank = xcd;
  const int g = sgr;

  unsigned gen = 0;
  unsigned* arr = s.bar + g * 32;
  unsigned* go = s.bar + 1024 + g * 32;

  bf16* hg = s.h + (long)g * ROWS * HH;
  bf16* hid_g = s.hid + (long)g * ROWS * HH;
  bf16* zg = s.z + (long)g * ROWS * ZZ;
  bf16* ag = s.a + (long)g * ROWS * HH;
  bf16* ghT_g = s.ghT + (long)g * 3072 * ROWS;

  float hreg[4] = {0.f, 0.f, 0.f, 0.f};

  for (int t = 0; t < TT; ++t) {
    // ===== P1: ranks 0-1: hid = elu(h@Wq1h + obs + b) (512 cols each)
    //           ranks 2-7: ghT = bf16(h@Whh)           (512 cols each)
    {
      const bool isHid = rank < 2;
      stage_bypass<1024>(hg, smem);
      if (isHid && tid < 256) {  // stage 16KB obs slab (cached, contiguous)
        const char* gb = (const char*)(s.obs_pre +
            (((long)g * TT + t) * HH + rank * 512) * 16);
        u32x4 v[4];
#pragma unroll
        for (int i = 0; i < 4; ++i) v[i] = *(const u32x4*)(gb + (tid * 4 + i) * 16);
#pragma unroll
        for (int i = 0; i < 4; ++i) {
          int u = tid * 4 + i;  // 16B unit; col = u>>1, half = u&1; stride 40
          *(u32x4*)(aux + (u >> 1) * 40 + (u & 1) * 16) = v[i];
        }
      }
      __syncthreads();
      const int fb = (isHid ? rank : rank - 2) * 32 + wid * 4;
      const bf16* P = isHid ? s.Pq1 : s.Phh;
      const bf16* bp[4];
#pragma unroll
      for (int nj = 0; nj < 4; ++nj) bp[nj] = P + ((long)(fb + nj) * 32) * 512 + lane * 8;
      bf16x8 br[2][4];
#pragma unroll
      for (int nj = 0; nj < 4; ++nj) { br[0][nj] = ldg8(bp[nj]); br[1][nj] = ldg8(bp[nj] + 512); }
      f32x4 acc[4] = {};
#pragma unroll
      for (int kk = 0; kk < 32; ++kk) {
        const int sl = kk & 1;
        bf16x8 a = ldfrag(smem + (kk >> 1) * 2048, lr, (kk & 1) * 64 + lk * 16);
#pragma unroll
        for (int nj = 0; nj < 4; ++nj) acc[nj] = MFMA(a, br[sl][nj], acc[nj]);
        if (kk + 2 < 32) {
#pragma unroll
          for (int nj = 0; nj < 4; ++nj) br[sl][nj] = ldg8(bp[nj] + (kk + 2) * 512);
        }
      }
      if (isHid) {
        const int colb = rank * 512 + wid * 64;
#pragma unroll
        for (int nj = 0; nj < 4; ++nj) {
          const int col = colb + nj * 16 + lr;
          const float bq = s.b_q1[col];
          unsigned long long o8 = *(const unsigned long long*)
              (aux + (wid * 64 + nj * 16 + lr) * 40 + lk * 8);
#pragma unroll
          for (int r = 0; r < 4; ++r) {
            float x = acc[nj][r] + bq + u2f((unsigned short)(o8 >> (16 * r)));
            ASTORE_U16(&hid_g[(lk * 4 + r) * HH + col], bf2u((bf16)eluf(x)));
          }
        }
      } else {
        const int colb = (rank - 2) * 512 + wid * 64;
#pragma unroll
        for (int nj = 0; nj < 4; ++nj) {
          const int cg = colb + nj * 16 + lr;
          unsigned long long pk = 0;
#pragma unroll
          for (int r = 0; r < 4; ++r)
            pk |= (unsigned long long)bf2u((bf16)acc[nj][r]) << (16 * r);
          ASTORE_U64(&ghT_g[(long)cg * ROWS + lk * 4], pk);
        }
      }
    }
    gbar(arr, go, rank, ++gen);

    // ===== P2: q-heads dual (loc|scale) + rsample; rank covers 32 j, 4 waves
    {
      stage_bypass<1024>(hid_g, smem);
      if (tid < 256) {  // stage 16KB eps tile (cached, contiguous), linear [16][256] f32
        const char* gb = (const char*)(s.eps + ((long)t * BB + (long)g * ROWS) * ZZ);
        u32x4 v[4];
#pragma unroll
        for (int i = 0; i < 4; ++i) v[i] = *(const u32x4*)(gb + (tid * 4 + i) * 16);
#pragma unroll
        for (int i = 0; i < 4; ++i) *(u32x4*)(aux + (tid * 4 + i) * 16) = v[i];
      }
      __syncthreads();
      if (wid < 4) {
        const int f = rank * 4 + wid;
        const bf16* bp = s.Pqh + ((long)f * 32) * 512 + lane * 8;
        bf16x8 br[4];
#pragma unroll
        for (int p = 0; p < 4; ++p) br[p] = ldg8(bp + p * 512);
        f32x4 acc = {};
#pragma unroll
        for (int kk = 0; kk < 32; ++kk) {
          bf16x8 a = ldfrag(smem + (kk >> 1) * 2048, lr, (kk & 1) * 64 + lk * 16);
          acc = MFMA(a, br[kk & 3], acc);
          if (kk + 4 < 32) br[kk & 3] = ldg8(bp + (kk + 4) * 512);
        }
        const int j0 = rank * 32 + wid * 8;
        const int jj = j0 + (lr & 7);
        const float bias = (lr < 8) ? s.b_qm[jj] : s.b_qs[jj];
#pragma unroll
        for (int r = 0; r < 4; ++r) {
          const int rl = lk * 4 + r;
          const long grow = (long)g * ROWS + rl;
          const long o = ((long)t * BB + grow) * ZZ + jj;
          float myv = acc[r] + bias;
          float sp = splusf(myv);
          float sc = __shfl(sp, lane + 8, 64);
          if (lr < 8) {
            float ev = *(const float*)(aux + ((long)rl * ZZ + jj) * 4);
            float zv = myv + sc * ev;
            s.dout[OFF_QL + o] = myv;
            s.dout[OFF_ZQ + o] = zv;
            ASTORE_U16(&zg[rl * ZZ + jj], bf2u((bf16)zv));
          } else {
            s.dout[OFF_QS + o] = sp;
          }
        }
      }
    }
    gbar(arr, go, rank, ++gen);

    // ===== P3: a = elu([z|act]@aggrW + b); rank covers 128 cols, K=320
    {
      stage_bypass<256>(zg, smem);
      stage_act(s.act_bf + ((long)t * BB + (long)g * ROWS) * AA, smem + 4 * 2048);
      __syncthreads();
      const int f = rank * 8 + wid;
      const bf16* bp = s.Pag + ((long)f * 10) * 512 + lane * 8;
      bf16x8 br[10];
#pragma unroll
      for (int p = 0; p < 10; ++p) br[p] = ldg8(bp + (long)p * 512);
      f32x4 acc = {};
#pragma unroll
      for (int kk = 0; kk < 10; ++kk) {
        bf16x8 a = ldfrag(smem + (kk >> 1) * 2048, lr, (kk & 1) * 64 + lk * 16);
        acc = MFMA(a, br[kk], acc);
      }
      const int col = rank * 128 + wid * 16 + lr;
      const float ba = s.b_ag[col];
#pragma unroll
      for (int r = 0; r < 4; ++r)
        ASTORE_U16(&ag[(lk * 4 + r) * HH + col], bf2u((bf16)eluf(acc[r] + ba)));
    }
    gbar(arr, go, rank, ++gen);

    // ===== P4: gi = a@Wih (3 gates x 16 j per wave) + GRU fuse; h in regs
    {
      stage_bypass<1024>(ag, smem);
      if (tid < 192) {  // stage 3 x 4KB ghT slabs (bypass, 64B chunks), stride 40
        u32x4 v[4];
        const int gate = (tid * 4) >> 8;
        const int uin = (tid * 4) & 255;
        const char* gb = (const char*)(ghT_g + ((long)gate * 1024 + rank * 128) * 16);
#pragma unroll
        for (int i = 0; i < 4; ++i) cload16(v[i], gb + (uin + i) * 16);
        asm volatile("s_waitcnt vmcnt(0)" ::: "memory");
        __builtin_amdgcn_sched_barrier(0);
#pragma unroll
        for (int i = 0; i < 4; ++i) {
          int u = uin + i;
          *(u32x4*)(aux + gate * 5120 + (u >> 1) * 40 + (u & 1) * 16) = v[i];
        }
      }
      __syncthreads();
      const int fb = rank * 8 + wid;
      const bf16* bp0 = s.Pih + ((long)(0 * 64 + fb) * 32) * 512 + lane * 8;
      const bf16* bp1 = s.Pih + ((long)(1 * 64 + fb) * 32) * 512 + lane * 8;
      const bf16* bp2 = s.Pih + ((long)(2 * 64 + fb) * 32) * 512 + lane * 8;
      bf16x8 b0[2], b1[2], b2[2];
      b0[0] = ldg8(bp0); b0[1] = ldg8(bp0 + 512);
      b1[0] = ldg8(bp1); b1[1] = ldg8(bp1 + 512);
      b2[0] = ldg8(bp2); b2[1] = ldg8(bp2 + 512);
      f32x4 gi0 = {}, gi1 = {}, gi2 = {};
#pragma unroll
      for (int kk = 0; kk < 32; ++kk) {
        const int sl = kk & 1;
        bf16x8 a = ldfrag(smem + (kk >> 1) * 2048, lr, (kk & 1) * 64 + lk * 16);
        gi0 = MFMA(a, b0[sl], gi0);
        gi1 = MFMA(a, b1[sl], gi1);
        gi2 = MFMA(a, b2[sl], gi2);
        if (kk + 2 < 32) {
          b0[sl] = ldg8(bp0 + (kk + 2) * 512);
          b1[sl] = ldg8(bp1 + (kk + 2) * 512);
          b2[sl] = ldg8(bp2 + (kk + 2) * 512);
        }
      }
      const int j = rank * 128 + wid * 16 + lr;
      const int jrel = wid * 16 + lr;
      unsigned long long ghp0 = *(const unsigned long long*)(aux + 0 * 5120 + jrel * 40 + lk * 8);
      unsigned long long ghp1 = *(const unsigned long long*)(aux + 1 * 5120 + jrel * 40 + lk * 8);
      unsigned long long ghp2 = *(const unsigned long long*)(aux + 2 * 5120 + jrel * 40 + lk * 8);
      const float bi0 = s.b_gih[j], bi1 = s.b_gih[HH + j], bi2 = s.b_gih[2 * HH + j];
      const float bh0 = s.b_ghh[j], bh1 = s.b_ghh[HH + j], bh2 = s.b_ghh[2 * HH + j];
#pragma unroll
      for (int r = 0; r < 4; ++r) {
        const int rl = lk * 4 + r;
        float rr = sigf(gi0[r] + bi0 + u2f((unsigned short)(ghp0 >> (16 * r))) + bh0);
        float zz = sigf(gi1[r] + bi1 + u2f((unsigned short)(ghp1 >> (16 * r))) + bh1);
        float nn = tanhf(gi2[r] + bi2 + rr * (u2f((unsigned short)(ghp2 >> (16 * r))) + bh2));
        float hnew = (1.f - zz) * nn + zz * hreg[r];
        hreg[r] = hnew;
        ASTORE_U16(&hg[rl * HH + j], bf2u((bf16)hnew));
        s.dout[(long)(t + 1) * BB * HH + ((long)g * ROWS + rl) * HH + j] = hnew;
      }
    }
    gbar(arr, go, rank, ++gen);
  }
}

// ---------------- weight packing (frag-linear) -------------------------------
__global__ void pack16(const float* __restrict__ W, bf16* __restrict__ dst,
                       int ld, int row0, int kts, int kmax, long total) {
  long idx = (long)blockIdx.x * 256 + threadIdx.x;
  if (idx >= total) return;
  int l = (int)(idx & 63);
  long fk = idx >> 6;
  int kt = (int)(fk % kts);
  int f = (int)(fk / kts);
  int col = f * 16 + (l & 15);
  int k = kt * 32 + (l >> 4) * 8;
  bf16x8 v;
#pragma unroll
  for (int e = 0; e < 8; ++e) {
    int kk = k + e;
    v[e] = (bf16)((kk < kmax) ? W[(long)(row0 + kk) * ld + col] : 0.f);
  }
  *(bf16x8*)&dst[idx * 8] = v;
}

__global__ void pack_qh(const float* __restrict__ Wm, const float* __restrict__ Ws,
                        bf16* __restrict__ dst) {
  long idx = (long)blockIdx.x * 256 + threadIdx.x;  // 32*32*64
  int l = (int)(idx & 63);
  long fk = idx >> 6;
  int f = (int)(fk >> 5);
  int k = (int)((fk & 31) * 32) + (l >> 4) * 8;
  const float* W = ((l & 15) < 8) ? Wm : Ws;
  int col = f * 8 + (l & 7);
  bf16x8 v;
#pragma unroll
  for (int e = 0; e < 8; ++e) v[e] = (bf16)W[(long)(k + e) * 256 + col];
  *(bf16x8*)&dst[idx * 8] = v;
}

// ---------------- batched GEMMs (prep / tails) ----------------

struct GArgs {
  const bf16* A; const float* Af;
  long lda;
  const bf16* Bt;
  int M, N, K;
  const float *b_p1, *b_pm, *b_ps;
  bf16* out_bf;
  float* dout;
};

// EPI: 5 = elu+bias -> bf16   6 = p-heads -> d_out   7 = obs_pre [g][t][col][16]
template <int BM, int BN, int EPI, bool AF32>
__global__ __launch_bounds__(256) void gemm_k(GArgs g) {
  constexpr int BK = 32;
  constexpr int WTM = BM / 2, WTN = BN / 2;
  constexpr int MR = WTM / 16, NR = WTN / 16;
  constexpr int CA = BM * 4 / 256, CB = BN * 4 / 256;
  __shared__ bf16 sA[BM * BK];
  __shared__ bf16 sB[BN * BK];
  const int nbm = g.M / BM;
  const int bm = blockIdx.x % nbm, bn = blockIdx.x / nbm;
  const int m0 = bm * BM, n0 = bn * BN;
  const int tid = threadIdx.x;
  const int wid = tid >> 6, lane = tid & 63;
  const int wm = wid & 1, wn = wid >> 1;
  const int lr = lane & 15, lk = lane >> 4;

  f32x4 acc[MR][NR] = {};

  for (int k0 = 0; k0 < g.K; k0 += BK) {
    __syncthreads();
    if constexpr (AF32) {
#pragma unroll
      for (int i = 0; i < CA; i++) {
        int c = tid + i * 256, row = c >> 2, kc = c & 3;
        const float* sp = g.Af + (long)(m0 + row) * g.lda + k0 + kc * 8;
        float4 v0 = *(const float4*)sp;
        float4 v1 = *(const float4*)(sp + 4);
        bf16x8 p;
        p[0] = (bf16)v0.x; p[1] = (bf16)v0.y; p[2] = (bf16)v0.z; p[3] = (bf16)v0.w;
        p[4] = (bf16)v1.x; p[5] = (bf16)v1.y; p[6] = (bf16)v1.z; p[7] = (bf16)v1.w;
        *(bf16x8*)&sA[c * 8] = p;
      }
    } else {
#pragma unroll
      for (int i = 0; i < CA; i++) {
        int c = tid + i * 256, row = c >> 2, kc = c & 3;
        GLL16(g.A + (long)(m0 + row) * g.lda + k0 + kc * 8, &sA[c * 8]);
      }
    }
#pragma unroll
    for (int i = 0; i < CB; i++) {
      int c = tid + i * 256, row = c >> 2, kc = c & 3;
      GLL16(g.Bt + (long)(n0 + row) * g.K + k0 + kc * 8, &sB[c * 8]);
    }
    __syncthreads();
    bf16x8 af[MR];
#pragma unroll
    for (int mi = 0; mi < MR; mi++)
      af[mi] = *(const bf16x8*)&sA[(wm * WTM + mi * 16 + lr) * BK + lk * 8];
#pragma unroll
    for (int nj = 0; nj < NR; nj++) {
      bf16x8 bfr = *(const bf16x8*)&sB[(wn * WTN + nj * 16 + lr) * BK + lk * 8];
#pragma unroll
      for (int mi = 0; mi < MR; mi++)
        acc[mi][nj] = MFMA(af[mi], bfr, acc[mi][nj]);
    }
  }

#pragma unroll
  for (int mi = 0; mi < MR; mi++)
#pragma unroll
    for (int nj = 0; nj < NR; nj++)
#pragma unroll
      for (int r = 0; r < 4; r++) {
        const int row = m0 + wm * WTM + mi * 16 + lk * 4 + r;
        const int col = n0 + wn * WTN + nj * 16 + lr;
        float v = acc[mi][nj][r];
        if constexpr (EPI == 7) {
          const int brow = row & 511, tt = row >> 9;
          g.out_bf[((((long)(brow >> 4) * TT + tt) * HH + col) << 4) + (brow & 15)] = (bf16)v;
        } else if constexpr (EPI == 5) {
          g.out_bf[(long)row * g.N + col] = (bf16)eluf(v + g.b_p1[col]);
        } else {
          int region = col >> 8, j = col & 255;
          float x = v + (region ? g.b_ps[j] : g.b_pm[j]);
          if (region) x = splusf(x);
          g.dout[(region ? OFF_PS : OFF_PL) + (long)row * ZZ + j] = x;
        }
      }
}

// dst[n*K + k] = bf16(src[(k + k_off)*ld + n])
__global__ void transpose_cvt(const float* __restrict__ src, bf16* __restrict__ dst,
                              int K, int N, int ld, int k_off) {
  __shared__ float tile[32][33];
  const int nb = blockIdx.x * 32, kb = blockIdx.y * 32;
  const int tx = threadIdx.x, ty = threadIdx.y;
#pragma unroll
  for (int j = 0; j < 32; j += 8)
    tile[ty + j][tx] = src[(long)(kb + ty + j + k_off) * ld + nb + tx];
  __syncthreads();
#pragma unroll
  for (int j = 0; j < 32; j += 8)
    dst[(long)(nb + ty + j) * K + kb + tx] = (bf16)tile[tx][ty + j];
}

__global__ void cvt_bf16(const float* __restrict__ src, bf16* __restrict__ dst, long n) {
  long i = ((long)blockIdx.x * blockDim.x + threadIdx.x) * 4;
  if (i < n) {
    float4 v = *(const float4*)(src + i);
    dst[i] = (bf16)v.x; dst[i + 1] = (bf16)v.y;
    dst[i + 2] = (bf16)v.z; dst[i + 3] = (bf16)v.w;
  }
}

__global__ void init_k(bf16* hbf, float* dout) {
  int i = blockIdx.x * 256 + threadIdx.x;
  hbf[i] = (bf16)0.f;
  dout[i] = 0.f;  // beliefs[0] = h0 = 0
}

extern "C" void kernel_launch(void* const* d_in, const int* in_sizes, int n_in,
                              void* d_out, int out_size, void* d_ws, size_t ws_size,
                              hipStream_t stream) {
  const float* obs  = (const float*)d_in[0];
  const float* act  = (const float*)d_in[1];
  const float* eps  = (const float*)d_in[2];
  const float* aggrW = (const float*)d_in[3];
  const float* aggrB = (const float*)d_in[4];
  const float* gWih = (const float*)d_in[5];
  const float* gWhh = (const float*)d_in[6];
  const float* gbih = (const float*)d_in[7];
  const float* gbhh = (const float*)d_in[8];
  const float* qW1  = (const float*)d_in[9];
  const float* qb1  = (const float*)d_in[10];
  const float* qWm  = (const float*)d_in[11];
  const float* qbm  = (const float*)d_in[12];
  const float* qWs  = (const float*)d_in[13];
  const float* qbs  = (const float*)d_in[14];
  const float* pW1  = (const float*)d_in[15];
  const float* pb1  = (const float*)d_in[16];
  const float* pWm  = (const float*)d_in[17];
  const float* pbm  = (const float*)d_in[18];
  const float* pWs  = (const float*)d_in[19];
  const float* pbs  = (const float*)d_in[20];
  float* dout = (float*)d_out;

  char* w = (char*)d_ws;
  size_t off = 0;
  auto alloc = [&](size_t bytes) -> char* {
    char* r = w + off;
    off = (off + bytes + 255) & ~(size_t)255;
    return r;
  };
  bf16* Pq1 = (bf16*)alloc((size_t)64 * 32 * 512 * 2);
  bf16* Pqh = (bf16*)alloc((size_t)32 * 32 * 512 * 2);
  bf16* Pag = (bf16*)alloc((size_t)64 * 10 * 512 * 2);
  bf16* Pih = (bf16*)alloc((size_t)192 * 32 * 512 * 2);
  bf16* Phh = (bf16*)alloc((size_t)192 * 32 * 512 * 2);
  bf16* WT_qobs = (bf16*)alloc((size_t)XX * HH * 2);
  bf16* WT_p1  = (bf16*)alloc((size_t)HH * HH * 2);
  bf16* WT_ph  = (bf16*)alloc((size_t)512 * HH * 2);
  bf16* obs_pre = (bf16*)alloc((size_t)TT * HH * BB * 2);  // [g][t][col][16]; p_hid alias
  bf16* p_hid  = obs_pre;
  bf16* act_bf = (bf16*)alloc((size_t)TT * BB * AA * 2);
  bf16* h_bf   = (bf16*)alloc((size_t)BB * HH * 2);
  bf16* hid_q  = (bf16*)alloc((size_t)BB * HH * 2);
  bf16* z_bf   = (bf16*)alloc((size_t)BB * ZZ * 2);
  bf16* a_buf  = (bf16*)alloc((size_t)BB * HH * 2);
  bf16* ghT    = (bf16*)alloc((size_t)BB * 3 * HH * 2);  // [g][3072][16] bf16
  unsigned* bar = (unsigned*)alloc(16384);
  (void)ws_size; (void)in_sizes; (void)n_in; (void)out_size;

  hipMemsetAsync(bar, 0, 16384, stream);

  pack16<<<512, 256, 0, stream>>>(qW1, Pq1, 1024, 1024, 32, 1024, 64L * 32 * 64);
  pack16<<<1536, 256, 0, stream>>>(gWhh, Phh, 3072, 0, 32, 1024, 192L * 32 * 64);
  pack16<<<1536, 256, 0, stream>>>(gWih, Pih, 3072, 0, 32, 1024, 192L * 32 * 64);
  pack16<<<160, 256, 0, stream>>>(aggrW, Pag, 1024, 0, 10, 320, 64L * 10 * 64);
  pack_qh<<<256, 256, 0, stream>>>(qWm, qWs, Pqh);

  dim3 tb(32, 8);
  transpose_cvt<<<dim3(32, 32), tb, 0, stream>>>(qW1, WT_qobs, 1024, 1024, 1024, 0);
  transpose_cvt<<<dim3(32, 32), tb, 0, stream>>>(pW1, WT_p1, 1024, 1024, 1024, 0);
  transpose_cvt<<<dim3(8, 32), tb, 0, stream>>>(pWm, WT_ph, 1024, 256, 256, 0);
  transpose_cvt<<<dim3(8, 32), tb, 0, stream>>>(pWs, WT_ph + 256 * 1024, 1024, 256, 256, 0);
  cvt_bf16<<<TT * BB * AA / 4 / 256, 256, 0, stream>>>(act, act_bf, (long)TT * BB * AA);
  init_k<<<BB * HH / 256, 256, 0, stream>>>(h_bf, dout);

  {  // obs_pre = (obs @ qW1[:X]) stored as [g][t][col][16]
    GArgs a{};
    a.Af = obs; a.lda = XX; a.Bt = WT_qobs;
    a.M = TT * BB; a.N = HH; a.K = XX; a.out_bf = obs_pre;
    gemm_k<128, 128, 7, true><<<(TT * BB / 128) * (HH / 128), 256, 0, stream>>>(a);
  }

  {  // persistent scan: rank = physical XCD, group = per-XCD ticket
    ScanArgs s{};
    s.Pq1 = Pq1; s.Pqh = Pqh; s.Pag = Pag; s.Pih = Pih; s.Phh = Phh;
    s.obs_pre = obs_pre; s.act_bf = act_bf;
    s.h = h_bf; s.hid = hid_q; s.z = z_bf; s.a = a_buf; s.ghT = ghT;
    s.b_q1 = qb1; s.b_ghh = gbhh; s.b_qm = qbm; s.b_qs = qbs;
    s.b_ag = aggrB; s.b_gih = gbih;
    s.eps = eps; s.dout = dout; s.bar = bar;
    scan_k<<<NBLK, NTHR, 0, stream>>>(s);
  }

  {  // p_hid = elu(beliefs[0:T*B] @ pW1 + b1)
    GArgs a{};
    a.Af = dout; a.lda = HH; a.Bt = WT_p1;
    a.M = TT * BB; a.N = HH; a.K = HH; a.out_bf = p_hid; a.b_p1 = pb1;
    gemm_k<128, 128, 5, true><<<(TT * BB / 128) * (HH / 128), 256, 0, stream>>>(a);
  }
  {  // p-heads
    GArgs a{};
    a.A = p_hid; a.lda = HH; a.Bt = WT_ph;
    a.M = TT * BB; a.N = 512; a.K = HH;
    a.b_pm = pbm; a.b_ps = pbs; a.dout = dout;
    gemm_k<128, 128, 6, false><<<(TT * BB / 128) * (512 / 128), 256, 0, stream>>>(a);
  }
}